// Round 11
// baseline (510.389 us; speedup 1.0000x reference)
//
#include <hip/hip_runtime.h>
#include <cstdint>

#define NN 50000
#define NE 800000
#define DPX 6250            // dst-partition size per XCD (NN/8)
#define SLICES 391          // ceil(NE/2048)

using short8  = __attribute__((ext_vector_type(8))) short;
using float4v = __attribute__((ext_vector_type(4))) float;
using floatx2 = __attribute__((ext_vector_type(2))) float;
typedef unsigned char uchar;

__device__ __forceinline__ ushort f2bf(float f) {
    uint u = __float_as_uint(f);
    uint r = (u + 0x7fffu + ((u >> 16) & 1u)) >> 16;
    return (ushort)r;
}
__device__ __forceinline__ float bf2f(uint u) {
    return __uint_as_float(u << 16);
}
__device__ __forceinline__ uchar f2fp8(float v) {
    return (uchar)((uint)__builtin_amdgcn_cvt_pk_fp8_f32(v, v, 0, false) & 0xffu);
}
__device__ __forceinline__ float fp8f(uint b) {
    floatx2 v = __builtin_amdgcn_cvt_pk_f32_fp8((int)b, false);
    return v.x;
}

// ---------------- fused tiny precompute + weight cvt + deg zero
__global__ __launch_bounds__(256) void k_prep2(const float* __restrict__ le1, const float* __restrict__ ae1,
                                               const float* __restrict__ le2, const float* __restrict__ ae2,
                                               const float* __restrict__ jkw, const float* __restrict__ jkb,
                                               const float* __restrict__ clw, const float* __restrict__ clb,
                                               const float* __restrict__ projw, const float* __restrict__ c1lin,
                                               const float* __restrict__ c2lin,
                                               const float* __restrict__ asrc1, const float* __restrict__ adst1,
                                               float* __restrict__ M, float* __restrict__ CW,
                                               float* __restrict__ cbp,
                                               ushort* __restrict__ w01b, ushort* __restrict__ c2b,
                                               float* __restrict__ Vmat, int* __restrict__ deg)
{
    int idx = blockIdx.x * 256 + threadIdx.x;
    if (idx < NN) deg[idx] = 0;
    if (idx < 32) {
        const float* le = (idx < 16) ? le1 : le2;
        const float* ae = (idx < 16) ? ae1 : ae2;
        int hk = idx & 15, h = hk >> 2, k = hk & 3;
        float s = 0.f;
        for (int c = 0; c < 32; ++c)
            s += le[(h * 32 + c) * 4 + k] * ae[h * 32 + c];
        M[idx] = s;
    } else if (idx < 1952) {
        int o = idx - 32;
        int r = o / 384, c = o - r * 384;
        float s = 0.f;
        for (int k = 0; k < 128; ++k)
            s += clw[r * 128 + k] * jkw[(size_t)k * 384 + c];
        CW[o] = s;
    } else if (idx < 1957) {
        int r = idx - 1952;
        float s = clb[r];
        for (int k = 0; k < 128; ++k)
            s += clw[r * 128 + k] * jkb[k];
        cbp[r] = s;
    } else if (idx >= 2048 && idx < 10240) {
        int o = idx - 2048;
        int r = o >> 5, c = o & 31;
        float v = 0.f;
        if (c < 16) v = (r < 128) ? projw[r * 16 + c] : c1lin[(r - 128) * 16 + c];
        w01b[o] = f2bf(v);
    } else if (idx >= 10240 && idx < 26624) {
        int o = idx - 10240;
        c2b[o] = f2bf(c2lin[o]);
    } else if (idx >= 26624 && idx < 26752) {
        int o = idx - 26624;
        const float* att = (o < 64) ? asrc1 : adst1;
        int oo = o & 63, h = oo >> 4, k = oo & 15;
        float s = 0.f;
        for (int c = 0; c < 32; ++c)
            s += c1lin[(h * 32 + c) * 16 + k] * att[h * 32 + c];
        Vmat[o] = s;
    }
}

// ---------------- conv1 attention coefficients straight from x
__global__ __launch_bounds__(256) void k_att1(const float* __restrict__ x,
                                              const float* __restrict__ V,
                                              float* __restrict__ as_o,
                                              float* __restrict__ ad_o)
{
    __shared__ float sV[128];
    int t = threadIdx.x;
    if (t < 128) sV[t] = V[t];
    __syncthreads();
    int n = blockIdx.x * 256 + t;
    if (n >= NN) return;
    const float4* xr = (const float4*)(x + (size_t)n * 16);
    float4 x0 = xr[0], x1 = xr[1], x2 = xr[2], x3 = xr[3];
    float xv[16] = {x0.x,x0.y,x0.z,x0.w, x1.x,x1.y,x1.z,x1.w,
                    x2.x,x2.y,x2.z,x2.w, x3.x,x3.y,x3.z,x3.w};
    float s[4], d[4];
    #pragma unroll
    for (int h = 0; h < 4; ++h) {
        float ss = 0.f, dd = 0.f;
        #pragma unroll
        for (int k = 0; k < 16; ++k) {
            ss += xv[k] * sV[h * 16 + k];
            dd += xv[k] * sV[64 + h * 16 + k];
        }
        s[h] = ss; d[h] = dd;
    }
    *(float4*)(as_o + (size_t)n * 4) = make_float4(s[0], s[1], s[2], s[3]);
    *(float4*)(ad_o + (size_t)n * 4) = make_float4(d[0], d[1], d[2], d[3]);
}

// ---------------- edge MLP + conv1 ex (bf16 x4) + conv2 a_edge (fp8 x4)
__global__ __launch_bounds__(256) void k_edge_mlp(const float* __restrict__ ea,
                                                  const float* __restrict__ w1,
                                                  const float* __restrict__ b1,
                                                  const float* __restrict__ w2,
                                                  const float* __restrict__ b2,
                                                  const int* __restrict__ ei,
                                                  const float* __restrict__ Mm,
                                                  const float* __restrict__ as1,
                                                  const float* __restrict__ ad1,
                                                  ushort* __restrict__ exb,
                                                  uint* __restrict__ aeq)
{
    __shared__ float sw1[256], sb1[32], sw2[128], sb2[4], sM[32];
    int t = threadIdx.x;
    sw1[t] = w1[t];
    if (t < 128) sw2[t] = w2[t];
    if (t < 32)  { sb1[t] = b1[t]; sM[t] = Mm[t]; }
    if (t < 4)   sb2[t] = b2[t];
    __syncthreads();
    int e = blockIdx.x * 256 + t;
    if (e >= NE) return;
    int src = ei[e], dst = ei[NE + e];
    float4 s4 = *(const float4*)(as1 + (size_t)src * 4);
    float4 d4 = *(const float4*)(ad1 + (size_t)dst * 4);
    float4 x0 = *(const float4*)(ea + (size_t)e * 8);
    float4 x1 = *(const float4*)(ea + (size_t)e * 8 + 4);
    float o0 = sb2[0], o1 = sb2[1], o2 = sb2[2], o3 = sb2[3];
    #pragma unroll
    for (int j = 0; j < 32; ++j) {
        const float* w = sw1 + j * 8;
        float s = sb1[j] + w[0]*x0.x + w[1]*x0.y + w[2]*x0.z + w[3]*x0.w
                         + w[4]*x1.x + w[5]*x1.y + w[6]*x1.z + w[7]*x1.w;
        s = fmaxf(s, 0.f);
        o0 += sw2[0*32+j] * s; o1 += sw2[1*32+j] * s;
        o2 += sw2[2*32+j] * s; o3 += sw2[3*32+j] * s;
    }
    float sa[4] = {s4.x, s4.y, s4.z, s4.w};
    float da[4] = {d4.x, d4.y, d4.z, d4.w};
    ushort exq[4];
    float a2[4];
    #pragma unroll
    for (int h = 0; h < 4; ++h) {
        float ae1 = sM[h*4+0]*o0 + sM[h*4+1]*o1 + sM[h*4+2]*o2 + sM[h*4+3]*o3;
        float al = sa[h] + da[h] + ae1;
        al = al > 0.f ? al : 0.2f * al;
        exq[h] = f2bf(__expf(al));
        a2[h] = sM[16+h*4+0]*o0 + sM[16+h*4+1]*o1 + sM[16+h*4+2]*o2 + sM[16+h*4+3]*o3;
    }
    *(uint2*)(exb + (size_t)e * 4) =
        make_uint2((uint)exq[0] | ((uint)exq[1] << 16), (uint)exq[2] | ((uint)exq[3] << 16));
    uint q = (uint)__builtin_amdgcn_cvt_pk_fp8_f32(a2[0], a2[1], 0, false);
    q = (uint)__builtin_amdgcn_cvt_pk_fp8_f32(a2[2], a2[3], (int)q, true);
    aeq[e] = q;
}

// ---------------- XCD-partitioned histogram
__global__ __launch_bounds__(256) void k_hist8(const int* __restrict__ ei, int* __restrict__ deg)
{
    int grp = blockIdx.x & 7;
    int base = (blockIdx.x >> 3) * 2048 + threadIdx.x;
    #pragma unroll
    for (int k = 0; k < 8; ++k) {
        int e = base + k * 256;
        if (e < NE) {
            int dst = ei[NE + e];
            if (dst / DPX == grp) atomicAdd(&deg[dst], 1);
        }
    }
}

// ---------------- scan ----------------
__global__ __launch_bounds__(256) void k_scan_blk(const int* __restrict__ deg,
                                                  int* __restrict__ loc,
                                                  int* __restrict__ bsum)
{
    __shared__ int tmp[256];
    int t = threadIdx.x;
    int i = blockIdx.x * 256 + t;
    int v = (i < NN) ? deg[i] : 0;
    tmp[t] = v;
    __syncthreads();
    #pragma unroll
    for (int o = 1; o < 256; o <<= 1) {
        int add = (t >= o) ? tmp[t - o] : 0;
        __syncthreads();
        tmp[t] += add;
        __syncthreads();
    }
    if (i < NN) loc[i] = tmp[t] - v;
    if (t == 255) bsum[blockIdx.x] = tmp[255];
}

__global__ __launch_bounds__(256) void k_scan_top(const int* __restrict__ bsum,
                                                  int* __restrict__ bcarry,
                                                  int* __restrict__ total_out, int nb)
{
    __shared__ int tmp[256];
    int t = threadIdx.x;
    int v = (t < nb) ? bsum[t] : 0;
    tmp[t] = v;
    __syncthreads();
    #pragma unroll
    for (int o = 1; o < 256; o <<= 1) {
        int add = (t >= o) ? tmp[t - o] : 0;
        __syncthreads();
        tmp[t] += add;
        __syncthreads();
    }
    if (t < nb) bcarry[t] = tmp[t] - v;
    if (t == 255) *total_out = tmp[255];
}

__global__ __launch_bounds__(256) void k_scan_add(const int* __restrict__ loc,
                                                  const int* __restrict__ bcarry,
                                                  int* __restrict__ off,
                                                  int* __restrict__ cur)
{
    int i = blockIdx.x * 256 + threadIdx.x;
    if (i < NN) {
        int o = loc[i] + bcarry[blockIdx.x];
        off[i] = o;
        cur[i] = o;
    }
}

// ---------------- XCD-partitioned scatter: ONE 16B entry {src16|dst16, ex01, ex23, ae2q}
__global__ __launch_bounds__(256) void k_scatter8(const int* __restrict__ ei,
                                                  const ushort* __restrict__ exb,
                                                  const uint* __restrict__ aeq,
                                                  int* __restrict__ cursor,
                                                  int4* __restrict__ csr4)
{
    int grp = blockIdx.x & 7;
    int base = (blockIdx.x >> 3) * 2048 + threadIdx.x;
    #pragma unroll
    for (int k = 0; k < 8; ++k) {
        int e = base + k * 256;
        if (e < NE) {
            int dst = ei[NE + e];
            if (dst / DPX == grp) {
                int src = ei[e];
                uint2 ex = *(const uint2*)(exb + (size_t)e * 4);
                uint q = aeq[e];
                int p = atomicAdd(&cursor[dst], 1);
                csr4[p] = make_int4((src << 16) | dst, (int)ex.x, (int)ex.y, (int)q);
            }
        }
    }
}

// ---------------- fused GEMM pair from x (K=16 pad 32): h0 bf16; xs1 fp8 head-major
__global__ __launch_bounds__(256) void k_gemm1(const float* __restrict__ x,
                                               const ushort* __restrict__ w01,
                                               const float* __restrict__ pbias,
                                               ushort* __restrict__ hcatb,
                                               uchar* __restrict__ xs8h, int M)
{
    int t = threadIdx.x;
    int wv = t >> 6, lane = t & 63;
    int quad = lane >> 4, r16 = lane & 15;
    int m0 = blockIdx.x * 128 + wv * 32;
    int ar0 = m0 + r16;      if (ar0 >= M) ar0 = M - 1;
    int ar1 = m0 + 16 + r16; if (ar1 >= M) ar1 = M - 1;
    short8 a0 = (short8){0,0,0,0,0,0,0,0}, a1 = a0;
    if (quad < 2) {
        const float* p0 = x + (size_t)ar0 * 16 + quad * 8;
        const float* p1 = x + (size_t)ar1 * 16 + quad * 8;
        float4 u0 = *(const float4*)p0, u1 = *(const float4*)(p0 + 4);
        float4 v0 = *(const float4*)p1, v1 = *(const float4*)(p1 + 4);
        a0[0]=(short)f2bf(u0.x); a0[1]=(short)f2bf(u0.y); a0[2]=(short)f2bf(u0.z); a0[3]=(short)f2bf(u0.w);
        a0[4]=(short)f2bf(u1.x); a0[5]=(short)f2bf(u1.y); a0[6]=(short)f2bf(u1.z); a0[7]=(short)f2bf(u1.w);
        a1[0]=(short)f2bf(v0.x); a1[1]=(short)f2bf(v0.y); a1[2]=(short)f2bf(v0.z); a1[3]=(short)f2bf(v0.w);
        a1[4]=(short)f2bf(v1.x); a1[5]=(short)f2bf(v1.y); a1[6]=(short)f2bf(v1.z); a1[7]=(short)f2bf(v1.w);
    }
    float4v acc[2][16];
    #pragma unroll
    for (int i = 0; i < 2; ++i)
        #pragma unroll
        for (int j = 0; j < 16; ++j) acc[i][j] = (float4v){0.f, 0.f, 0.f, 0.f};
    #pragma unroll
    for (int nt = 0; nt < 16; ++nt) {
        short8 b = *(const short8*)(w01 + (size_t)(nt * 16 + r16) * 32 + quad * 8);
        acc[0][nt] = __builtin_amdgcn_mfma_f32_16x16x32_bf16(a0, b, acc[0][nt], 0, 0, 0);
        acc[1][nt] = __builtin_amdgcn_mfma_f32_16x16x32_bf16(a1, b, acc[1][nt], 0, 0, 0);
    }
    #pragma unroll
    for (int rt = 0; rt < 2; ++rt) {
        #pragma unroll
        for (int nt = 0; nt < 16; ++nt) {
            int col = (nt & 7) * 16 + r16;
            float bv = (nt < 8) ? pbias[col] : 0.f;
            #pragma unroll
            for (int r = 0; r < 4; ++r) {
                int row = m0 + rt * 16 + quad * 4 + r;
                if (row < M) {
                    float v = acc[rt][nt][r] + bv;
                    if (nt < 8) hcatb[(size_t)row * 384 + col] = f2bf(v);
                    else        xs8h[((size_t)(col >> 5) * NN + row) * 32 + (col & 31)] = f2fp8(v);
                }
            }
        }
    }
}

// ---------------- conv2 GEMM (K=128), xs fp8 head-major out, fused att reduction
__global__ __launch_bounds__(256) void k_gemm2(const ushort* __restrict__ A,
                                               const ushort* __restrict__ W,
                                               const float* __restrict__ atts,
                                               const float* __restrict__ attd,
                                               uchar* __restrict__ xs8h,
                                               float* __restrict__ as_o,
                                               float* __restrict__ ad_o, int M)
{
    __shared__ float sAs[128], sAd[128];
    int t = threadIdx.x;
    if (t < 128) { sAs[t] = atts[t]; sAd[t] = attd[t]; }
    __syncthreads();
    int wv = t >> 6, lane = t & 63;
    int quad = lane >> 4, r16 = lane & 15;
    int m0 = blockIdx.x * 128 + wv * 32;
    float4v acc[2][8];
    #pragma unroll
    for (int i = 0; i < 2; ++i)
        #pragma unroll
        for (int j = 0; j < 8; ++j) acc[i][j] = (float4v){0.f, 0.f, 0.f, 0.f};
    int ar0 = m0 + r16;      if (ar0 >= M) ar0 = M - 1;
    int ar1 = m0 + 16 + r16; if (ar1 >= M) ar1 = M - 1;
    const ushort* a0p = A + (size_t)ar0 * 384 + quad * 8;
    const ushort* a1p = A + (size_t)ar1 * 384 + quad * 8;
    const ushort* wp  = W + (size_t)r16 * 128 + quad * 8;
    #pragma unroll
    for (int k0 = 0; k0 < 128; k0 += 32) {
        short8 a0 = *(const short8*)(a0p + k0);
        short8 a1 = *(const short8*)(a1p + k0);
        #pragma unroll
        for (int nt = 0; nt < 8; ++nt) {
            short8 b = *(const short8*)(wp + (size_t)(nt * 16) * 128 + k0);
            acc[0][nt] = __builtin_amdgcn_mfma_f32_16x16x32_bf16(a0, b, acc[0][nt], 0, 0, 0);
            acc[1][nt] = __builtin_amdgcn_mfma_f32_16x16x32_bf16(a1, b, acc[1][nt], 0, 0, 0);
        }
    }
    #pragma unroll
    for (int rt = 0; rt < 2; ++rt) {
        #pragma unroll
        for (int nt = 0; nt < 8; ++nt) {
            int col = nt * 16 + r16;
            #pragma unroll
            for (int r = 0; r < 4; ++r) {
                int row = m0 + rt * 16 + quad * 4 + r;
                if (row < M)
                    xs8h[((size_t)(col >> 5) * NN + row) * 32 + (col & 31)] = f2fp8(acc[rt][nt][r]);
            }
        }
        #pragma unroll
        for (int r = 0; r < 4; ++r) {
            int row = m0 + rt * 16 + quad * 4 + r;
            float sh[4], dh[4];
            #pragma unroll
            for (int h = 0; h < 4; ++h) {
                int cA = h * 32 + r16, cB = cA + 16;
                sh[h] = acc[rt][2*h][r] * sAs[cA] + acc[rt][2*h+1][r] * sAs[cB];
                dh[h] = acc[rt][2*h][r] * sAd[cA] + acc[rt][2*h+1][r] * sAd[cB];
            }
            #pragma unroll
            for (int o = 1; o < 16; o <<= 1) {
                #pragma unroll
                for (int h = 0; h < 4; ++h) {
                    sh[h] += __shfl_xor(sh[h], o, 64);
                    dh[h] += __shfl_xor(dh[h], o, 64);
                }
            }
            if (r16 == 0 && row < M) {
                *(float4*)(as_o + (size_t)row * 4) = make_float4(sh[0], sh[1], sh[2], sh[3]);
                *(float4*)(ad_o + (size_t)row * 4) = make_float4(dh[0], dh[1], dh[2], dh[3]);
            }
        }
    }
}

// ---------------- conv2 numerator: sequential in-place rewrite of csr4 ex words
__global__ __launch_bounds__(256) void k_soft2csr(int4* __restrict__ csr4,
                                                  const float* __restrict__ as_in,
                                                  const float* __restrict__ ad_in)
{
    int i = blockIdx.x * 256 + threadIdx.x;
    if (i >= NE) return;
    int4 en = csr4[i];
    uint sd = (uint)en.x;
    int src = (int)(sd >> 16), dst = (int)(sd & 0xffffu);
    float4 s4 = *(const float4*)(as_in + (size_t)src * 4);
    float4 d4 = *(const float4*)(ad_in + (size_t)dst * 4);
    floatx2 a01 = __builtin_amdgcn_cvt_pk_f32_fp8(en.w, false);
    floatx2 a23 = __builtin_amdgcn_cvt_pk_f32_fp8(en.w, true);
    float av[4] = {a01.x, a01.y, a23.x, a23.y};
    float sa[4] = {s4.x, s4.y, s4.z, s4.w};
    float da[4] = {d4.x, d4.y, d4.z, d4.w};
    ushort exq[4];
    #pragma unroll
    for (int h = 0; h < 4; ++h) {
        float al = sa[h] + da[h] + av[h];
        al = al > 0.f ? al : 0.2f * al;
        exq[h] = f2bf(__expf(al));
    }
    en.y = (int)((uint)exq[0] | ((uint)exq[1] << 16));
    en.z = (int)((uint)exq[2] | ((uint)exq[3] << 16));
    csr4[i] = en;
}

// ---------------- head-partitioned aggregation: head = (blockIdx&7)>>1 (XCD-pair local)
// wave = one (node, head); lanes: c = lane&31 channel, j = lane>>5 edge parity
__global__ __launch_bounds__(256) void k_aggH(const int* __restrict__ off,
                                              const int4* __restrict__ csr4,
                                              const uchar* __restrict__ xs8h,
                                              ushort* __restrict__ aggH,
                                              float* __restrict__ denH)
{
    int g = blockIdx.x & 7;
    int head = g >> 1;
    int bi = blockIdx.x >> 3;
    int wave = threadIdx.x >> 6, lane = threadIdx.x & 63;
    int n = (g & 1) * (NN / 2) + bi * 4 + wave;
    if (n >= NN) return;
    int i0 = off[n], i1 = off[n + 1];
    int j = lane >> 5, c = lane & 31;
    int hsel = head >> 1, hsh = (head & 1) << 4;
    const uchar* xt = xs8h + (size_t)head * NN * 32 + c;
    float a = 0.f, den = 0.f;
    int i = i0 + j;
    for (; i + 6 < i1; i += 8) {
        int4 e0 = csr4[i], e1 = csr4[i+2], e2 = csr4[i+4], e3 = csr4[i+6];
        uint b0 = xt[(size_t)((uint)e0.x >> 16) * 32];
        uint b1 = xt[(size_t)((uint)e1.x >> 16) * 32];
        uint b2 = xt[(size_t)((uint)e2.x >> 16) * 32];
        uint b3 = xt[(size_t)((uint)e3.x >> 16) * 32];
        float w0 = bf2f(((uint)(hsel ? e0.z : e0.y) >> hsh) & 0xffffu);
        float w1 = bf2f(((uint)(hsel ? e1.z : e1.y) >> hsh) & 0xffffu);
        float w2 = bf2f(((uint)(hsel ? e2.z : e2.y) >> hsh) & 0xffffu);
        float w3 = bf2f(((uint)(hsel ? e3.z : e3.y) >> hsh) & 0xffffu);
        a = fmaf(fp8f(b0), w0, a); a = fmaf(fp8f(b1), w1, a);
        a = fmaf(fp8f(b2), w2, a); a = fmaf(fp8f(b3), w3, a);
        den += (w0 + w1) + (w2 + w3);
    }
    for (; i < i1; i += 2) {
        int4 e0 = csr4[i];
        uint b0 = xt[(size_t)((uint)e0.x >> 16) * 32];
        float w0 = bf2f(((uint)(hsel ? e0.z : e0.y) >> hsh) & 0xffffu);
        a = fmaf(fp8f(b0), w0, a);
        den += w0;
    }
    a += __shfl_xor(a, 32, 64);
    den += __shfl_xor(den, 32, 64);
    if (lane < 32) aggH[((size_t)head * NN + n) * 32 + c] = f2bf(a);
    if (lane == 0) denH[(size_t)head * NN + n] = den;
}

// ---------------- epilogue: normalize + bias + ELU + residual + LayerNorm -> hcat col
__global__ __launch_bounds__(256) void k_epi(const ushort* __restrict__ aggH,
                                             const float* __restrict__ denH,
                                             const float* __restrict__ bias,
                                             const ushort* __restrict__ residb,
                                             const float* __restrict__ g,
                                             const float* __restrict__ bln,
                                             ushort* __restrict__ outb)
{
    __shared__ float red[4][2];
    int t = threadIdx.x;
    int n = blockIdx.x * 2 + (t >> 7);
    int c = t & 127;
    float r = 0.f;
    if (n < NN) {
        int h = c >> 5, cc = c & 31;
        float a = bf2f(aggH[((size_t)h * NN + n) * 32 + cc]);
        float den = denH[(size_t)h * NN + n];
        float v = a / (den + 1e-16f) + bias[c];
        v = v > 0.f ? v : (__expf(v) - 1.f);
        r = v + bf2f(residb[(size_t)n * 384 + c]);
    }
    float s = r, sq = r * r;
    #pragma unroll
    for (int o = 32; o > 0; o >>= 1) {
        s  += __shfl_down(s, o, 64);
        sq += __shfl_down(sq, o, 64);
    }
    int wave = t >> 6;
    if ((t & 63) == 0) { red[wave][0] = s; red[wave][1] = sq; }
    __syncthreads();
    int base = (t >> 7) * 2;
    float S  = red[base][0] + red[base + 1][0];
    float SQ = red[base][1] + red[base + 1][1];
    float mu = S * (1.f / 128.f);
    float var = SQ * (1.f / 128.f) - mu * mu;
    float rs = rsqrtf(var + 1e-5f);
    if (n < NN)
        outb[(size_t)n * 384 + c] = f2bf((r - mu) * rs * g[c] + bln[c]);
}

// ---------------- fused jk+classifier
__global__ __launch_bounds__(256) void k_cls(const ushort* __restrict__ hcatb,
                                             const float* __restrict__ CW,
                                             const float* __restrict__ cbp,
                                             float* __restrict__ out)
{
    __shared__ float sCW[1920], scb[5];
    int t = threadIdx.x;
    for (int i = t; i < 1920; i += 256) sCW[i] = CW[i];
    if (t < 5) scb[t] = cbp[t];
    __syncthreads();
    int n = blockIdx.x * 256 + t;
    if (n >= NN) return;
    float acc[5] = {scb[0], scb[1], scb[2], scb[3], scb[4]};
    const uint2* hr = (const uint2*)(hcatb + (size_t)n * 384);
    #pragma unroll 4
    for (int q = 0; q < 96; ++q) {
        uint2 p = hr[q];
        float v0 = bf2f(p.x & 0xffffu), v1 = bf2f(p.x >> 16);
        float v2 = bf2f(p.y & 0xffffu), v3 = bf2f(p.y >> 16);
        #pragma unroll
        for (int o = 0; o < 5; ++o) {
            const float* w = sCW + o * 384 + q * 4;
            acc[o] += v0*w[0] + v1*w[1] + v2*w[2] + v3*w[3];
        }
    }
    float m = acc[0];
    #pragma unroll
    for (int o = 1; o < 5; ++o) m = fmaxf(m, acc[o]);
    float sum = 0.f;
    #pragma unroll
    for (int o = 0; o < 5; ++o) sum += __expf(acc[o] - m);
    float lse = __logf(sum) + m;
    float* op = out + (size_t)n * 5;
    #pragma unroll
    for (int o = 0; o < 5; ++o) op[o] = acc[o] - lse;
}

extern "C" void kernel_launch(void* const* d_in, const int* in_sizes, int n_in,
                              void* d_out, int out_size, void* d_ws, size_t ws_size,
                              hipStream_t stream)
{
    (void)in_sizes; (void)n_in; (void)out_size; (void)ws_size;
    const float* x        = (const float*)d_in[0];
    const int*   ei       = (const int*)d_in[1];
    const float* eattr    = (const float*)d_in[2];
    const float* ee_w1    = (const float*)d_in[3];
    const float* ee_b1    = (const float*)d_in[4];
    const float* ee_w2    = (const float*)d_in[5];
    const float* ee_b2    = (const float*)d_in[6];
    const float* proj_w   = (const float*)d_in[7];
    const float* proj_b   = (const float*)d_in[8];
    const float* c1_lin   = (const float*)d_in[9];
    const float* c1_asrc  = (const float*)d_in[10];
    const float* c1_adst  = (const float*)d_in[11];
    const float* c1_ledge = (const float*)d_in[12];
    const float* c1_aedge = (const float*)d_in[13];
    const float* c1_bias  = (const float*)d_in[14];
    const float* c2_lin   = (const float*)d_in[15];
    const float* c2_asrc  = (const float*)d_in[16];
    const float* c2_adst  = (const float*)d_in[17];
    const float* c2_ledge = (const float*)d_in[18];
    const float* c2_aedge = (const float*)d_in[19];
    const float* c2_bias  = (const float*)d_in[20];
    const float* n1_g     = (const float*)d_in[21];
    const float* n1_b     = (const float*)d_in[22];
    const float* n2_g     = (const float*)d_in[23];
    const float* n2_b     = (const float*)d_in[24];
    const float* jk_w     = (const float*)d_in[25];
    const float* jk_b     = (const float*)d_in[26];
    const float* cls_w    = (const float*)d_in[27];
    const float* cls_b    = (const float*)d_in[28];
    float* out = (float*)d_out;
    float* ws  = (float*)d_ws;

    // ---- workspace layout (float-element offsets, 16B-aligned)
    const size_t oM   = 0;                           // 32 (+pad)
    const size_t oCW  = 64;                          // 1920
    const size_t oCB  = 1984;                        // 5 (+pad to 2048)
    const size_t oV   = 2048;                        // 128 -> 2176
    const size_t oEX  = 2176;                        // exb bf16 NE*2 f
    const size_t oAQ  = oEX + (size_t)NE * 2;        // aeq uint NE f
    const size_t oHB  = oAQ + (size_t)NE;            // hcatb bf16 NN*192 f
    const size_t oXS  = oHB + (size_t)NN * 192;      // xs8h fp8 4*NN*32 B = NN*32 f
    const size_t oAG  = oXS + (size_t)NN * 32;       // aggH bf16 4*NN*32 = NN*64 f
    const size_t oDN  = oAG + (size_t)NN * 64;       // denH 4*NN f
    const size_t oWB  = oDN + (size_t)NN * 4;        // w01b + c2b = 12288 f
    const size_t oAS  = oWB + 12288;                 // NN*4
    const size_t oAD  = oAS + (size_t)NN * 4;        // NN*4
    const size_t oI   = oAD + (size_t)NN * 4;        // int region

    float*  Mmat  = ws + oM;
    float*  CW    = ws + oCW;
    float*  cbp   = ws + oCB;
    float*  Vmat  = ws + oV;
    ushort* exb   = (ushort*)(ws + oEX);
    uint*   aeq   = (uint*)(ws + oAQ);
    ushort* hcatb = (ushort*)(ws + oHB);
    uchar*  xs8h  = (uchar*)(ws + oXS);
    ushort* aggH  = (ushort*)(ws + oAG);
    float*  denH  = ws + oDN;
    ushort* w01b  = (ushort*)(ws + oWB);             // [256,32]
    ushort* c2b   = w01b + 8192;                     // [128,128]
    float*  as_b  = ws + oAS;
    float*  ad_b  = ws + oAD;
    int*    ip    = (int*)(ws + oI);
    int*    deg   = ip;                              // NN
    int*    loc   = ip + NN;                         // NN
    int*    off   = ip + 2 * NN;                     // NN+16
    int*    cur   = ip + 3 * NN + 16;                // NN
    int*    bsum  = ip + 4 * NN + 16;                // 256
    int*    bcar  = ip + 4 * NN + 272;               // 256 (+16 pad)
    int4*   csr4  = (int4*)(ip + 4 * NN + 544);      // NE int4 (16B aligned)

    const int EB  = (NE + 255) / 256;          // 3125
    const int NB  = (NN + 255) / 256;          // 196
    const int GB  = (NN + 127) / 128;          // 391
    const int PB  = SLICES * 8;                // 3128
    const int AB  = (NN / 2 / 4) * 8;          // 50000 aggH blocks
    const int PEB = NN / 2;                    // 25000 epi blocks

    // ---- precompute + deg zero
    k_prep2<<<NB, 256, 0, stream>>>(c1_ledge, c1_aedge, c2_ledge, c2_aedge,
                                    jk_w, jk_b, cls_w, cls_b,
                                    proj_w, c1_lin, c2_lin, c1_asrc, c1_adst,
                                    Mmat, CW, cbp, w01b, c2b, Vmat, deg);
    // ---- conv1 att coefficients + edge MLP
    k_att1<<<NB, 256, 0, stream>>>(x, Vmat, as_b, ad_b);
    k_edge_mlp<<<EB, 256, 0, stream>>>(eattr, ee_w1, ee_b1, ee_w2, ee_b2, ei,
                                       Mmat, as_b, ad_b, exb, aeq);
    // ---- CSR build (XCD-partitioned), ex1 + ae2q embedded in 16B entries
    k_hist8<<<PB, 256, 0, stream>>>(ei, deg);
    k_scan_blk<<<NB, 256, 0, stream>>>(deg, loc, bsum);
    k_scan_top<<<1, 256, 0, stream>>>(bsum, bcar, off + NN, NB);
    k_scan_add<<<NB, 256, 0, stream>>>(loc, bcar, off, cur);
    k_scatter8<<<PB, 256, 0, stream>>>(ei, exb, aeq, cur, csr4);

    // ---- h0 + xs1 (head-major fp8) in one pass from fp32 x
    k_gemm1<<<GB, 256, 0, stream>>>(x, w01b, proj_b, hcatb, xs8h, NN);

    // ---- conv1: head-partitioned aggregation + epilogue
    k_aggH<<<AB, 256, 0, stream>>>(off, csr4, xs8h, aggH, denH);
    k_epi<<<PEB, 256, 0, stream>>>(aggH, denH, c1_bias, hcatb, n1_g, n1_b, hcatb + 128);

    // ---- conv2
    k_gemm2<<<GB, 256, 0, stream>>>(hcatb + 128, c2b, c2_asrc, c2_adst,
                                    xs8h, as_b, ad_b, NN);
    k_soft2csr<<<EB, 256, 0, stream>>>(csr4, as_b, ad_b);
    k_aggH<<<AB, 256, 0, stream>>>(off, csr4, xs8h, aggH, denH);
    k_epi<<<PEB, 256, 0, stream>>>(aggH, denH, c2_bias, hcatb + 128, n2_g, n2_b, hcatb + 256);

    // ---- fused jk+classifier+log_softmax
    k_cls<<<NB, 256, 0, stream>>>(hcatb, CW, cbp, out);
}

// Round 12
// 379.443 us; speedup vs baseline: 1.3451x; 1.3451x over previous
//
#include <hip/hip_runtime.h>
#include <cstdint>

#define NN 50000
#define NE 800000
#define DPX 6250            // dst-partition size per XCD (NN/8)
#define SLICES 391          // ceil(NE/2048)

using short8  = __attribute__((ext_vector_type(8))) short;
using float4v = __attribute__((ext_vector_type(4))) float;
using floatx2 = __attribute__((ext_vector_type(2))) float;
typedef unsigned char uchar;

__device__ __forceinline__ ushort f2bf(float f) {
    uint u = __float_as_uint(f);
    uint r = (u + 0x7fffu + ((u >> 16) & 1u)) >> 16;
    return (ushort)r;
}
__device__ __forceinline__ float bf2f(uint u) {
    return __uint_as_float(u << 16);
}
__device__ __forceinline__ uchar f2fp8(float v) {
    return (uchar)((uint)__builtin_amdgcn_cvt_pk_fp8_f32(v, v, 0, false) & 0xffu);
}

// ---------------- fused tiny precompute + weight cvt + deg zero
__global__ __launch_bounds__(256) void k_prep2(const float* __restrict__ le1, const float* __restrict__ ae1,
                                               const float* __restrict__ le2, const float* __restrict__ ae2,
                                               const float* __restrict__ jkw, const float* __restrict__ jkb,
                                               const float* __restrict__ clw, const float* __restrict__ clb,
                                               const float* __restrict__ projw, const float* __restrict__ c1lin,
                                               const float* __restrict__ c2lin,
                                               const float* __restrict__ asrc1, const float* __restrict__ adst1,
                                               float* __restrict__ M, float* __restrict__ CW,
                                               float* __restrict__ cbp,
                                               ushort* __restrict__ w01b, ushort* __restrict__ c2b,
                                               float* __restrict__ Vmat, int* __restrict__ deg)
{
    int idx = blockIdx.x * 256 + threadIdx.x;
    if (idx < NN) deg[idx] = 0;
    if (idx < 32) {
        const float* le = (idx < 16) ? le1 : le2;
        const float* ae = (idx < 16) ? ae1 : ae2;
        int hk = idx & 15, h = hk >> 2, k = hk & 3;
        float s = 0.f;
        for (int c = 0; c < 32; ++c)
            s += le[(h * 32 + c) * 4 + k] * ae[h * 32 + c];
        M[idx] = s;
    } else if (idx < 1952) {
        int o = idx - 32;
        int r = o / 384, c = o - r * 384;
        float s = 0.f;
        for (int k = 0; k < 128; ++k)
            s += clw[r * 128 + k] * jkw[(size_t)k * 384 + c];
        CW[o] = s;
    } else if (idx < 1957) {
        int r = idx - 1952;
        float s = clb[r];
        for (int k = 0; k < 128; ++k)
            s += clw[r * 128 + k] * jkb[k];
        cbp[r] = s;
    } else if (idx >= 2048 && idx < 10240) {
        int o = idx - 2048;
        int r = o >> 5, c = o & 31;
        float v = 0.f;
        if (c < 16) v = (r < 128) ? projw[r * 16 + c] : c1lin[(r - 128) * 16 + c];
        w01b[o] = f2bf(v);
    } else if (idx >= 10240 && idx < 26624) {
        int o = idx - 10240;
        c2b[o] = f2bf(c2lin[o]);
    } else if (idx >= 26624 && idx < 26752) {
        int o = idx - 26624;
        const float* att = (o < 64) ? asrc1 : adst1;
        int oo = o & 63, h = oo >> 4, k = oo & 15;
        float s = 0.f;
        for (int c = 0; c < 32; ++c)
            s += c1lin[(h * 32 + c) * 16 + k] * att[h * 32 + c];
        Vmat[o] = s;
    }
}

// ---------------- conv1 attention coefficients straight from x
__global__ __launch_bounds__(256) void k_att1(const float* __restrict__ x,
                                              const float* __restrict__ V,
                                              float* __restrict__ as_o,
                                              float* __restrict__ ad_o)
{
    __shared__ float sV[128];
    int t = threadIdx.x;
    if (t < 128) sV[t] = V[t];
    __syncthreads();
    int n = blockIdx.x * 256 + t;
    if (n >= NN) return;
    const float4* xr = (const float4*)(x + (size_t)n * 16);
    float4 x0 = xr[0], x1 = xr[1], x2 = xr[2], x3 = xr[3];
    float xv[16] = {x0.x,x0.y,x0.z,x0.w, x1.x,x1.y,x1.z,x1.w,
                    x2.x,x2.y,x2.z,x2.w, x3.x,x3.y,x3.z,x3.w};
    float s[4], d[4];
    #pragma unroll
    for (int h = 0; h < 4; ++h) {
        float ss = 0.f, dd = 0.f;
        #pragma unroll
        for (int k = 0; k < 16; ++k) {
            ss += xv[k] * sV[h * 16 + k];
            dd += xv[k] * sV[64 + h * 16 + k];
        }
        s[h] = ss; d[h] = dd;
    }
    *(float4*)(as_o + (size_t)n * 4) = make_float4(s[0], s[1], s[2], s[3]);
    *(float4*)(ad_o + (size_t)n * 4) = make_float4(d[0], d[1], d[2], d[3]);
}

// ---------------- edge MLP + conv1 ex (bf16 x4) + conv2 a_edge (fp8 x4)
__global__ __launch_bounds__(256) void k_edge_mlp(const float* __restrict__ ea,
                                                  const float* __restrict__ w1,
                                                  const float* __restrict__ b1,
                                                  const float* __restrict__ w2,
                                                  const float* __restrict__ b2,
                                                  const int* __restrict__ ei,
                                                  const float* __restrict__ Mm,
                                                  const float* __restrict__ as1,
                                                  const float* __restrict__ ad1,
                                                  ushort* __restrict__ exb,
                                                  uint* __restrict__ aeq)
{
    __shared__ float sw1[256], sb1[32], sw2[128], sb2[4], sM[32];
    int t = threadIdx.x;
    sw1[t] = w1[t];
    if (t < 128) sw2[t] = w2[t];
    if (t < 32)  { sb1[t] = b1[t]; sM[t] = Mm[t]; }
    if (t < 4)   sb2[t] = b2[t];
    __syncthreads();
    int e = blockIdx.x * 256 + t;
    if (e >= NE) return;
    int src = ei[e], dst = ei[NE + e];
    float4 s4 = *(const float4*)(as1 + (size_t)src * 4);
    float4 d4 = *(const float4*)(ad1 + (size_t)dst * 4);
    float4 x0 = *(const float4*)(ea + (size_t)e * 8);
    float4 x1 = *(const float4*)(ea + (size_t)e * 8 + 4);
    float o0 = sb2[0], o1 = sb2[1], o2 = sb2[2], o3 = sb2[3];
    #pragma unroll
    for (int j = 0; j < 32; ++j) {
        const float* w = sw1 + j * 8;
        float s = sb1[j] + w[0]*x0.x + w[1]*x0.y + w[2]*x0.z + w[3]*x0.w
                         + w[4]*x1.x + w[5]*x1.y + w[6]*x1.z + w[7]*x1.w;
        s = fmaxf(s, 0.f);
        o0 += sw2[0*32+j] * s; o1 += sw2[1*32+j] * s;
        o2 += sw2[2*32+j] * s; o3 += sw2[3*32+j] * s;
    }
    float sa[4] = {s4.x, s4.y, s4.z, s4.w};
    float da[4] = {d4.x, d4.y, d4.z, d4.w};
    ushort exq[4];
    float a2[4];
    #pragma unroll
    for (int h = 0; h < 4; ++h) {
        float ae1 = sM[h*4+0]*o0 + sM[h*4+1]*o1 + sM[h*4+2]*o2 + sM[h*4+3]*o3;
        float al = sa[h] + da[h] + ae1;
        al = al > 0.f ? al : 0.2f * al;
        exq[h] = f2bf(__expf(al));
        a2[h] = sM[16+h*4+0]*o0 + sM[16+h*4+1]*o1 + sM[16+h*4+2]*o2 + sM[16+h*4+3]*o3;
    }
    *(uint2*)(exb + (size_t)e * 4) =
        make_uint2((uint)exq[0] | ((uint)exq[1] << 16), (uint)exq[2] | ((uint)exq[3] << 16));
    uint q = (uint)__builtin_amdgcn_cvt_pk_fp8_f32(a2[0], a2[1], 0, false);
    q = (uint)__builtin_amdgcn_cvt_pk_fp8_f32(a2[2], a2[3], (int)q, true);
    aeq[e] = q;
}

// ---------------- XCD-partitioned histogram
__global__ __launch_bounds__(256) void k_hist8(const int* __restrict__ ei, int* __restrict__ deg)
{
    int grp = blockIdx.x & 7;
    int base = (blockIdx.x >> 3) * 2048 + threadIdx.x;
    #pragma unroll
    for (int k = 0; k < 8; ++k) {
        int e = base + k * 256;
        if (e < NE) {
            int dst = ei[NE + e];
            if (dst / DPX == grp) atomicAdd(&deg[dst], 1);
        }
    }
}

// ---------------- scan ----------------
__global__ __launch_bounds__(256) void k_scan_blk(const int* __restrict__ deg,
                                                  int* __restrict__ loc,
                                                  int* __restrict__ bsum)
{
    __shared__ int tmp[256];
    int t = threadIdx.x;
    int i = blockIdx.x * 256 + t;
    int v = (i < NN) ? deg[i] : 0;
    tmp[t] = v;
    __syncthreads();
    #pragma unroll
    for (int o = 1; o < 256; o <<= 1) {
        int add = (t >= o) ? tmp[t - o] : 0;
        __syncthreads();
        tmp[t] += add;
        __syncthreads();
    }
    if (i < NN) loc[i] = tmp[t] - v;
    if (t == 255) bsum[blockIdx.x] = tmp[255];
}

__global__ __launch_bounds__(256) void k_scan_top(const int* __restrict__ bsum,
                                                  int* __restrict__ bcarry,
                                                  int* __restrict__ total_out, int nb)
{
    __shared__ int tmp[256];
    int t = threadIdx.x;
    int v = (t < nb) ? bsum[t] : 0;
    tmp[t] = v;
    __syncthreads();
    #pragma unroll
    for (int o = 1; o < 256; o <<= 1) {
        int add = (t >= o) ? tmp[t - o] : 0;
        __syncthreads();
        tmp[t] += add;
        __syncthreads();
    }
    if (t < nb) bcarry[t] = tmp[t] - v;
    if (t == 255) *total_out = tmp[255];
}

__global__ __launch_bounds__(256) void k_scan_add(const int* __restrict__ loc,
                                                  const int* __restrict__ bcarry,
                                                  int* __restrict__ off,
                                                  int* __restrict__ cur)
{
    int i = blockIdx.x * 256 + threadIdx.x;
    if (i < NN) {
        int o = loc[i] + bcarry[blockIdx.x];
        off[i] = o;
        cur[i] = o;
    }
}

// ---------------- XCD-partitioned scatter: ONE 16B entry {src16|dst16, ex01, ex23, ae2q}
__global__ __launch_bounds__(256) void k_scatter8(const int* __restrict__ ei,
                                                  const ushort* __restrict__ exb,
                                                  const uint* __restrict__ aeq,
                                                  int* __restrict__ cursor,
                                                  int4* __restrict__ csr4)
{
    int grp = blockIdx.x & 7;
    int base = (blockIdx.x >> 3) * 2048 + threadIdx.x;
    #pragma unroll
    for (int k = 0; k < 8; ++k) {
        int e = base + k * 256;
        if (e < NE) {
            int dst = ei[NE + e];
            if (dst / DPX == grp) {
                int src = ei[e];
                uint2 ex = *(const uint2*)(exb + (size_t)e * 4);
                uint q = aeq[e];
                int p = atomicAdd(&cursor[dst], 1);
                csr4[p] = make_int4((src << 16) | dst, (int)ex.x, (int)ex.y, (int)q);
            }
        }
    }
}

// ---------------- fused GEMM pair from x (K=16 pad 32): h0 bf16; xs1 fp8 node-major
__global__ __launch_bounds__(256) void k_gemm1(const float* __restrict__ x,
                                               const ushort* __restrict__ w01,
                                               const float* __restrict__ pbias,
                                               ushort* __restrict__ hcatb,
                                               uchar* __restrict__ xs8, int M)
{
    int t = threadIdx.x;
    int wv = t >> 6, lane = t & 63;
    int quad = lane >> 4, r16 = lane & 15;
    int m0 = blockIdx.x * 128 + wv * 32;
    int ar0 = m0 + r16;      if (ar0 >= M) ar0 = M - 1;
    int ar1 = m0 + 16 + r16; if (ar1 >= M) ar1 = M - 1;
    short8 a0 = (short8){0,0,0,0,0,0,0,0}, a1 = a0;
    if (quad < 2) {
        const float* p0 = x + (size_t)ar0 * 16 + quad * 8;
        const float* p1 = x + (size_t)ar1 * 16 + quad * 8;
        float4 u0 = *(const float4*)p0, u1 = *(const float4*)(p0 + 4);
        float4 v0 = *(const float4*)p1, v1 = *(const float4*)(p1 + 4);
        a0[0]=(short)f2bf(u0.x); a0[1]=(short)f2bf(u0.y); a0[2]=(short)f2bf(u0.z); a0[3]=(short)f2bf(u0.w);
        a0[4]=(short)f2bf(u1.x); a0[5]=(short)f2bf(u1.y); a0[6]=(short)f2bf(u1.z); a0[7]=(short)f2bf(u1.w);
        a1[0]=(short)f2bf(v0.x); a1[1]=(short)f2bf(v0.y); a1[2]=(short)f2bf(v0.z); a1[3]=(short)f2bf(v0.w);
        a1[4]=(short)f2bf(v1.x); a1[5]=(short)f2bf(v1.y); a1[6]=(short)f2bf(v1.z); a1[7]=(short)f2bf(v1.w);
    }
    float4v acc[2][16];
    #pragma unroll
    for (int i = 0; i < 2; ++i)
        #pragma unroll
        for (int j = 0; j < 16; ++j) acc[i][j] = (float4v){0.f, 0.f, 0.f, 0.f};
    #pragma unroll
    for (int nt = 0; nt < 16; ++nt) {
        short8 b = *(const short8*)(w01 + (size_t)(nt * 16 + r16) * 32 + quad * 8);
        acc[0][nt] = __builtin_amdgcn_mfma_f32_16x16x32_bf16(a0, b, acc[0][nt], 0, 0, 0);
        acc[1][nt] = __builtin_amdgcn_mfma_f32_16x16x32_bf16(a1, b, acc[1][nt], 0, 0, 0);
    }
    #pragma unroll
    for (int rt = 0; rt < 2; ++rt) {
        #pragma unroll
        for (int nt = 0; nt < 16; ++nt) {
            int col = (nt & 7) * 16 + r16;
            float bv = (nt < 8) ? pbias[col] : 0.f;
            #pragma unroll
            for (int r = 0; r < 4; ++r) {
                int row = m0 + rt * 16 + quad * 4 + r;
                if (row < M) {
                    float v = acc[rt][nt][r] + bv;
                    if (nt < 8) hcatb[(size_t)row * 384 + col] = f2bf(v);
                    else        xs8[(size_t)row * 128 + col] = f2fp8(v);
                }
            }
        }
    }
}

// ---------------- conv2 GEMM (K=128), xs fp8 node-major out, fused att reduction
__global__ __launch_bounds__(256) void k_gemm2(const ushort* __restrict__ A,
                                               const ushort* __restrict__ W,
                                               const float* __restrict__ atts,
                                               const float* __restrict__ attd,
                                               uchar* __restrict__ xs8,
                                               float* __restrict__ as_o,
                                               float* __restrict__ ad_o, int M)
{
    __shared__ float sAs[128], sAd[128];
    int t = threadIdx.x;
    if (t < 128) { sAs[t] = atts[t]; sAd[t] = attd[t]; }
    __syncthreads();
    int wv = t >> 6, lane = t & 63;
    int quad = lane >> 4, r16 = lane & 15;
    int m0 = blockIdx.x * 128 + wv * 32;
    float4v acc[2][8];
    #pragma unroll
    for (int i = 0; i < 2; ++i)
        #pragma unroll
        for (int j = 0; j < 8; ++j) acc[i][j] = (float4v){0.f, 0.f, 0.f, 0.f};
    int ar0 = m0 + r16;      if (ar0 >= M) ar0 = M - 1;
    int ar1 = m0 + 16 + r16; if (ar1 >= M) ar1 = M - 1;
    const ushort* a0p = A + (size_t)ar0 * 384 + quad * 8;
    const ushort* a1p = A + (size_t)ar1 * 384 + quad * 8;
    const ushort* wp  = W + (size_t)r16 * 128 + quad * 8;
    #pragma unroll
    for (int k0 = 0; k0 < 128; k0 += 32) {
        short8 a0 = *(const short8*)(a0p + k0);
        short8 a1 = *(const short8*)(a1p + k0);
        #pragma unroll
        for (int nt = 0; nt < 8; ++nt) {
            short8 b = *(const short8*)(wp + (size_t)(nt * 16) * 128 + k0);
            acc[0][nt] = __builtin_amdgcn_mfma_f32_16x16x32_bf16(a0, b, acc[0][nt], 0, 0, 0);
            acc[1][nt] = __builtin_amdgcn_mfma_f32_16x16x32_bf16(a1, b, acc[1][nt], 0, 0, 0);
        }
    }
    #pragma unroll
    for (int rt = 0; rt < 2; ++rt) {
        #pragma unroll
        for (int nt = 0; nt < 8; ++nt) {
            int col = nt * 16 + r16;
            #pragma unroll
            for (int r = 0; r < 4; ++r) {
                int row = m0 + rt * 16 + quad * 4 + r;
                if (row < M)
                    xs8[(size_t)row * 128 + col] = f2fp8(acc[rt][nt][r]);
            }
        }
        #pragma unroll
        for (int r = 0; r < 4; ++r) {
            int row = m0 + rt * 16 + quad * 4 + r;
            float sh[4], dh[4];
            #pragma unroll
            for (int h = 0; h < 4; ++h) {
                int cA = h * 32 + r16, cB = cA + 16;
                sh[h] = acc[rt][2*h][r] * sAs[cA] + acc[rt][2*h+1][r] * sAs[cB];
                dh[h] = acc[rt][2*h][r] * sAd[cA] + acc[rt][2*h+1][r] * sAd[cB];
            }
            #pragma unroll
            for (int o = 1; o < 16; o <<= 1) {
                #pragma unroll
                for (int h = 0; h < 4; ++h) {
                    sh[h] += __shfl_xor(sh[h], o, 64);
                    dh[h] += __shfl_xor(dh[h], o, 64);
                }
            }
            if (r16 == 0 && row < M) {
                *(float4*)(as_o + (size_t)row * 4) = make_float4(sh[0], sh[1], sh[2], sh[3]);
                *(float4*)(ad_o + (size_t)row * 4) = make_float4(dh[0], dh[1], dh[2], dh[3]);
            }
        }
    }
}

// ---------------- conv2 numerator: sequential in-place rewrite of csr4 ex words
__global__ __launch_bounds__(256) void k_soft2csr(int4* __restrict__ csr4,
                                                  const float* __restrict__ as_in,
                                                  const float* __restrict__ ad_in)
{
    int i = blockIdx.x * 256 + threadIdx.x;
    if (i >= NE) return;
    int4 en = csr4[i];
    uint sd = (uint)en.x;
    int src = (int)(sd >> 16), dst = (int)(sd & 0xffffu);
    float4 s4 = *(const float4*)(as_in + (size_t)src * 4);
    float4 d4 = *(const float4*)(ad_in + (size_t)dst * 4);
    floatx2 a01 = __builtin_amdgcn_cvt_pk_f32_fp8(en.w, false);
    floatx2 a23 = __builtin_amdgcn_cvt_pk_f32_fp8(en.w, true);
    float av[4] = {a01.x, a01.y, a23.x, a23.y};
    float sa[4] = {s4.x, s4.y, s4.z, s4.w};
    float da[4] = {d4.x, d4.y, d4.z, d4.w};
    ushort exq[4];
    #pragma unroll
    for (int h = 0; h < 4; ++h) {
        float al = sa[h] + da[h] + av[h];
        al = al > 0.f ? al : 0.2f * al;
        exq[h] = f2bf(__expf(al));
    }
    en.y = (int)((uint)exq[0] | ((uint)exq[1] << 16));
    en.z = (int)((uint)exq[2] | ((uint)exq[3] << 16));
    csr4[i] = en;
}

// ---------------- CSR aggregation (ex embedded, xs fp8 node-major) + epilogue fused
__global__ __launch_bounds__(256) void k_agg2(const int* __restrict__ off,
                                              const int4* __restrict__ csr4,
                                              const uchar* __restrict__ xs8,
                                              const float* __restrict__ bias,
                                              const ushort* __restrict__ residb,
                                              const float* __restrict__ g,
                                              const float* __restrict__ bln,
                                              ushort* __restrict__ outb)
{
    int wave = threadIdx.x >> 6;
    int lane = threadIdx.x & 63;
    int n = blockIdx.x * 4 + wave;
    if (n >= NN) return;
    int i0 = off[n], i1 = off[n + 1];
    int c0 = lane * 2;
    int h = lane >> 4;
    int hsel = h >> 1, hsh = (h & 1) << 4;
    float a0 = 0.f, a1 = 0.f, den = 0.f;
    int i = i0;
    for (; i + 8 <= i1; i += 8) {
        int4 en[8];
        #pragma unroll
        for (int j = 0; j < 8; ++j) en[j] = csr4[i + j];
        ushort p[8];
        #pragma unroll
        for (int j = 0; j < 8; ++j)
            p[j] = *(const ushort*)(xs8 + (size_t)((uint)en[j].x >> 16) * 128 + c0);
        #pragma unroll
        for (int j = 0; j < 8; ++j) {
            uint exsel = (uint)(hsel ? en[j].z : en[j].y);
            float w = bf2f((exsel >> hsh) & 0xffffu);
            floatx2 v = __builtin_amdgcn_cvt_pk_f32_fp8((int)(uint)p[j], false);
            a0 = fmaf(v.x, w, a0);
            a1 = fmaf(v.y, w, a1);
            den += w;
        }
    }
    for (; i + 4 <= i1; i += 4) {
        int4 en[4];
        #pragma unroll
        for (int j = 0; j < 4; ++j) en[j] = csr4[i + j];
        ushort p[4];
        #pragma unroll
        for (int j = 0; j < 4; ++j)
            p[j] = *(const ushort*)(xs8 + (size_t)((uint)en[j].x >> 16) * 128 + c0);
        #pragma unroll
        for (int j = 0; j < 4; ++j) {
            uint exsel = (uint)(hsel ? en[j].z : en[j].y);
            float w = bf2f((exsel >> hsh) & 0xffffu);
            floatx2 v = __builtin_amdgcn_cvt_pk_f32_fp8((int)(uint)p[j], false);
            a0 = fmaf(v.x, w, a0);
            a1 = fmaf(v.y, w, a1);
            den += w;
        }
    }
    for (; i < i1; ++i) {
        int4 en = csr4[i];
        ushort p0 = *(const ushort*)(xs8 + (size_t)((uint)en.x >> 16) * 128 + c0);
        uint exsel = (uint)(hsel ? en.z : en.y);
        float w = bf2f((exsel >> hsh) & 0xffffu);
        floatx2 v = __builtin_amdgcn_cvt_pk_f32_fp8((int)(uint)p0, false);
        a0 = fmaf(v.x, w, a0);
        a1 = fmaf(v.y, w, a1);
        den += w;
    }
    float inv = 1.f / (den + 1e-16f);
    float v0 = a0 * inv + bias[c0];
    float v1 = a1 * inv + bias[c0 + 1];
    v0 = v0 > 0.f ? v0 : (__expf(v0) - 1.f);
    v1 = v1 > 0.f ? v1 : (__expf(v1) - 1.f);
    uint rp = *(const uint*)(residb + (size_t)n * 384 + c0);
    float r0 = v0 + bf2f(rp & 0xffffu);
    float r1 = v1 + bf2f(rp >> 16);
    float ssum = r0 + r1, ssq = r0 * r0 + r1 * r1;
    #pragma unroll
    for (int o = 1; o < 64; o <<= 1) {
        ssum += __shfl_xor(ssum, o, 64);
        ssq  += __shfl_xor(ssq, o, 64);
    }
    float mu = ssum * (1.f / 128.f);
    float var = ssq * (1.f / 128.f) - mu * mu;
    float rs = rsqrtf(var + 1e-5f);
    float o0 = (r0 - mu) * rs * g[c0] + bln[c0];
    float o1 = (r1 - mu) * rs * g[c0 + 1] + bln[c0 + 1];
    uint pk = (uint)f2bf(o0) | ((uint)f2bf(o1) << 16);
    *(uint*)(outb + (size_t)n * 384 + c0) = pk;
}

// ---------------- fused jk+classifier
__global__ __launch_bounds__(256) void k_cls(const ushort* __restrict__ hcatb,
                                             const float* __restrict__ CW,
                                             const float* __restrict__ cbp,
                                             float* __restrict__ out)
{
    __shared__ float sCW[1920], scb[5];
    int t = threadIdx.x;
    for (int i = t; i < 1920; i += 256) sCW[i] = CW[i];
    if (t < 5) scb[t] = cbp[t];
    __syncthreads();
    int n = blockIdx.x * 256 + t;
    if (n >= NN) return;
    float acc[5] = {scb[0], scb[1], scb[2], scb[3], scb[4]};
    const uint2* hr = (const uint2*)(hcatb + (size_t)n * 384);
    #pragma unroll 4
    for (int q = 0; q < 96; ++q) {
        uint2 p = hr[q];
        float v0 = bf2f(p.x & 0xffffu), v1 = bf2f(p.x >> 16);
        float v2 = bf2f(p.y & 0xffffu), v3 = bf2f(p.y >> 16);
        #pragma unroll
        for (int o = 0; o < 5; ++o) {
            const float* w = sCW + o * 384 + q * 4;
            acc[o] += v0*w[0] + v1*w[1] + v2*w[2] + v3*w[3];
        }
    }
    float m = acc[0];
    #pragma unroll
    for (int o = 1; o < 5; ++o) m = fmaxf(m, acc[o]);
    float sum = 0.f;
    #pragma unroll
    for (int o = 0; o < 5; ++o) sum += __expf(acc[o] - m);
    float lse = __logf(sum) + m;
    float* op = out + (size_t)n * 5;
    #pragma unroll
    for (int o = 0; o < 5; ++o) op[o] = acc[o] - lse;
}

extern "C" void kernel_launch(void* const* d_in, const int* in_sizes, int n_in,
                              void* d_out, int out_size, void* d_ws, size_t ws_size,
                              hipStream_t stream)
{
    (void)in_sizes; (void)n_in; (void)out_size; (void)ws_size;
    const float* x        = (const float*)d_in[0];
    const int*   ei       = (const int*)d_in[1];
    const float* eattr    = (const float*)d_in[2];
    const float* ee_w1    = (const float*)d_in[3];
    const float* ee_b1    = (const float*)d_in[4];
    const float* ee_w2    = (const float*)d_in[5];
    const float* ee_b2    = (const float*)d_in[6];
    const float* proj_w   = (const float*)d_in[7];
    const float* proj_b   = (const float*)d_in[8];
    const float* c1_lin   = (const float*)d_in[9];
    const float* c1_asrc  = (const float*)d_in[10];
    const float* c1_adst  = (const float*)d_in[11];
    const float* c1_ledge = (const float*)d_in[12];
    const float* c1_aedge = (const float*)d_in[13];
    const float* c1_bias  = (const float*)d_in[14];
    const float* c2_lin   = (const float*)d_in[15];
    const float* c2_asrc  = (const float*)d_in[16];
    const float* c2_adst  = (const float*)d_in[17];
    const float* c2_ledge = (const float*)d_in[18];
    const float* c2_aedge = (const float*)d_in[19];
    const float* c2_bias  = (const float*)d_in[20];
    const float* n1_g     = (const float*)d_in[21];
    const float* n1_b     = (const float*)d_in[22];
    const float* n2_g     = (const float*)d_in[23];
    const float* n2_b     = (const float*)d_in[24];
    const float* jk_w     = (const float*)d_in[25];
    const float* jk_b     = (const float*)d_in[26];
    const float* cls_w    = (const float*)d_in[27];
    const float* cls_b    = (const float*)d_in[28];
    float* out = (float*)d_out;
    float* ws  = (float*)d_ws;

    // ---- workspace layout (float-element offsets, 16B-aligned)
    const size_t oM   = 0;                           // 32 (+pad)
    const size_t oCW  = 64;                          // 1920
    const size_t oCB  = 1984;                        // 5 (+pad to 2048)
    const size_t oV   = 2048;                        // 128 -> 2176
    const size_t oEX  = 2176;                        // exb bf16 NE*2 f
    const size_t oAQ  = oEX + (size_t)NE * 2;        // aeq uint NE f
    const size_t oHB  = oAQ + (size_t)NE;            // hcatb bf16 NN*192 f
    const size_t oXS  = oHB + (size_t)NN * 192;      // xs8 fp8 NN*128 B = NN*32 f
    const size_t oWB  = oXS + (size_t)NN * 32;       // w01b + c2b = 12288 f
    const size_t oAS  = oWB + 12288;                 // NN*4
    const size_t oAD  = oAS + (size_t)NN * 4;        // NN*4
    const size_t oI   = oAD + (size_t)NN * 4;        // int region

    float*  Mmat  = ws + oM;
    float*  CW    = ws + oCW;
    float*  cbp   = ws + oCB;
    float*  Vmat  = ws + oV;
    ushort* exb   = (ushort*)(ws + oEX);
    uint*   aeq   = (uint*)(ws + oAQ);
    ushort* hcatb = (ushort*)(ws + oHB);
    uchar*  xs8   = (uchar*)(ws + oXS);
    ushort* w01b  = (ushort*)(ws + oWB);             // [256,32]
    ushort* c2b   = w01b + 8192;                     // [128,128]
    float*  as_b  = ws + oAS;
    float*  ad_b  = ws + oAD;
    int*    ip    = (int*)(ws + oI);
    int*    deg   = ip;                              // NN
    int*    loc   = ip + NN;                         // NN
    int*    off   = ip + 2 * NN;                     // NN+16
    int*    cur   = ip + 3 * NN + 16;                // NN
    int*    bsum  = ip + 4 * NN + 16;                // 256
    int*    bcar  = ip + 4 * NN + 272;               // 256 (+16 pad)
    int4*   csr4  = (int4*)(ip + 4 * NN + 544);      // NE int4 (16B aligned)

    const int EB  = (NE + 255) / 256;          // 3125
    const int NB  = (NN + 255) / 256;          // 196
    const int GB  = (NN + 127) / 128;          // 391
    const int WB2 = (NN + 3) / 4;              // 12500
    const int PB  = SLICES * 8;                // 3128

    // ---- precompute + deg zero
    k_prep2<<<NB, 256, 0, stream>>>(c1_ledge, c1_aedge, c2_ledge, c2_aedge,
                                    jk_w, jk_b, cls_w, cls_b,
                                    proj_w, c1_lin, c2_lin, c1_asrc, c1_adst,
                                    Mmat, CW, cbp, w01b, c2b, Vmat, deg);
    // ---- conv1 att coefficients + edge MLP
    k_att1<<<NB, 256, 0, stream>>>(x, Vmat, as_b, ad_b);
    k_edge_mlp<<<EB, 256, 0, stream>>>(eattr, ee_w1, ee_b1, ee_w2, ee_b2, ei,
                                       Mmat, as_b, ad_b, exb, aeq);
    // ---- CSR build (XCD-partitioned), ex1 + ae2q embedded in one 16B entry
    k_hist8<<<PB, 256, 0, stream>>>(ei, deg);
    k_scan_blk<<<NB, 256, 0, stream>>>(deg, loc, bsum);
    k_scan_top<<<1, 256, 0, stream>>>(bsum, bcar, off + NN, NB);
    k_scan_add<<<NB, 256, 0, stream>>>(loc, bcar, off, cur);
    k_scatter8<<<PB, 256, 0, stream>>>(ei, exb, aeq, cur, csr4);

    // ---- h0 + xs1 (fp8) in one pass from fp32 x
    k_gemm1<<<GB, 256, 0, stream>>>(x, w01b, proj_b, hcatb, xs8, NN);

    // ---- conv1 aggregation (all heads in one pass)
    k_agg2<<<WB2, 256, 0, stream>>>(off, csr4, xs8, c1_bias, hcatb,
                                    n1_g, n1_b, hcatb + 128);

    // ---- conv2
    k_gemm2<<<GB, 256, 0, stream>>>(hcatb + 128, c2b, c2_asrc, c2_adst,
                                    xs8, as_b, ad_b, NN);
    k_soft2csr<<<EB, 256, 0, stream>>>(csr4, as_b, ad_b);
    k_agg2<<<WB2, 256, 0, stream>>>(off, csr4, xs8, c2_bias, hcatb + 128,
                                    n2_g, n2_b, hcatb + 256);

    // ---- fused jk+classifier+log_softmax
    k_cls<<<NB, 256, 0, stream>>>(hcatb, CW, cbp, out);
}